// Round 5
// baseline (82.854 us; speedup 1.0000x reference)
//
#include <hip/hip_runtime.h>

#define B_    16
#define CIN   64
#define COUT  128
#define H_    32
#define W_    32

typedef __attribute__((ext_vector_type(8)))  short  short8;    // 8 bf16 = 4 VGPRs
typedef __attribute__((ext_vector_type(16))) float  float16v;  // 32x32 MFMA C/D

// float -> bf16 bits; exact for small integers (|q| <= 127 needs 7 mantissa bits)
__device__ __forceinline__ unsigned short f2bf(float q) {
  return (unsigned short)(__builtin_bit_cast(unsigned int, q) >> 16);
}

// All-lanes max of a 256-entry array (written by prep), no LDS, no sync.
__device__ __forceinline__ float wave_max256(const float* __restrict__ p) {
  const int lane = threadIdx.x & 63;
  float m = fmaxf(fmaxf(p[lane], p[lane + 64]),
                  fmaxf(p[lane + 128], p[lane + 192]));
#pragma unroll
  for (int off = 32; off > 0; off >>= 1)
    m = fmaxf(m, __shfl_down(m, off, 64));
  return __shfl(m, 0, 64);
}

// ---------------------------------------------------------------------------
// Dispatch 1 (fused): blocks [0,256): per-block max|x| -> bmx[blk].
// Blocks [256,288): each redundantly scans ALL of w (288 KB, L1/L2) for the
// exact global max|w|, then quantizes+packs its 1/32 slice of qw:
//   qw bf16 [s:9][k16:4][kb:2][cout:128][8 cin]  (MFMA-lane order)
// Quantization mirrors the reference exactly: s = max/127 (IEEE div),
// rintf (round-half-even), clip +-127. Plain stores, poison-safe.
// ---------------------------------------------------------------------------
__global__ __launch_bounds__(256) void prep_kernel(
    const float4* __restrict__ x4, const float4* __restrict__ w4,
    const float* __restrict__ wflat,
    float* __restrict__ bmx, float* __restrict__ bmw,
    unsigned short* __restrict__ qw) {
  const int t = threadIdx.x;
  __shared__ float sm[4];
  if (blockIdx.x < 256) {
    // ---- per-block max|x| over 1/256 of x ----
    const int tid = blockIdx.x * 256 + t;
    float mx = 0.0f;
#pragma unroll
    for (int k = 0; k < 4; ++k) {          // 262144 float4 / 65536 = 4
      float4 v = x4[tid + k * 65536];
      mx = fmaxf(mx, fmaxf(fmaxf(fabsf(v.x), fabsf(v.y)),
                           fmaxf(fabsf(v.z), fabsf(v.w))));
    }
#pragma unroll
    for (int off = 32; off > 0; off >>= 1)
      mx = fmaxf(mx, __shfl_down(mx, off, 64));
    if ((t & 63) == 0) sm[t >> 6] = mx;
    __syncthreads();
    if (t == 0)
      bmx[blockIdx.x] = fmaxf(fmaxf(sm[0], sm[1]), fmaxf(sm[2], sm[3]));
  } else {
    // ---- full scan of w (18432 float4) for the exact global max ----
    float mw = 0.0f;
    for (int i = t; i < 18432; i += 256) {
      float4 v = w4[i];
      mw = fmaxf(mw, fmaxf(fmaxf(fabsf(v.x), fabsf(v.y)),
                           fmaxf(fabsf(v.z), fabsf(v.w))));
    }
#pragma unroll
    for (int off = 32; off > 0; off >>= 1)
      mw = fmaxf(mw, __shfl_down(mw, off, 64));
    if ((t & 63) == 0) sm[t >> 6] = mw;
    __syncthreads();
    const float m = fmaxf(fmaxf(sm[0], sm[1]), fmaxf(sm[2], sm[3]));
    if (t == 0) bmw[0] = m;                 // all w-blocks store same value
    const float s = m / 127.0f;
    // ---- quantize + pack this block's 2304-element slice ----
    const int base = (blockIdx.x - 256) * 2304;
#pragma unroll
    for (int mIt = 0; mIt < 9; ++mIt) {
      const int i = base + t + mIt * 256;
      float q = rintf(wflat[i] / s);
      q = fminf(fmaxf(q, -127.0f), 127.0f);
      // i = ((o*64 + c)*3 + kh)*3 + kw
      const int kw = i % 3; int j = i / 3;
      const int kh = j % 3; j /= 3;
      const int c = j & 63; const int o = j >> 6;
      const int sidx = kh * 3 + kw;
      const int k16 = c >> 4, kb2 = (c >> 3) & 1, e = c & 7;
      qw[(size_t)((((sidx * 4 + k16) * 2 + kb2) * 128 + o)) * 8 + e] = f2bf(q);
    }
  }
}

// ---------------------------------------------------------------------------
// Dispatch 2: conv with INLINE x-quantization. Block = (y row, batch b),
// 4 waves (cout groups), 2 blocks/CU. Prologue: quantize the 3 needed input
// rows (exact reference math) straight into LDS in MFMA-lane layout
// [r:3][k16:4][kb:2][xs:34][8 cin] (13056 B); halo = zero chunks. Main loop:
// A-frags from global qw (L2-hot, contiguous per half-wave), B-frags via
// ds_read_b128. 36 x mfma_f32_32x32x16_bf16 into two acc chains (exact).
// D: col=lane&31 (pixel x), row=(reg&3)+8*(reg>>2)+4*(lane>>5) (cout).
// ---------------------------------------------------------------------------
__global__ __launch_bounds__(256, 2) void conv_mfma_kernel(
    const float* __restrict__ x,            // [16][64][32][32] fp32
    const unsigned short* __restrict__ qw,  // [9][4][2][128][8] bf16
    const float* __restrict__ bmx, const float* __restrict__ bmw,
    const float* __restrict__ bias, float* __restrict__ out) {
  __shared__ __align__(16) unsigned short lds[3 * 272 * 8];  // 13056 B
  const int t    = threadIdx.x;
  const int lane = t & 63;
  const int wv   = t >> 6;            // cout group
  const int col  = lane & 31;         // pixel x (B) / cout row (A)
  const int kb   = lane >> 5;         // k-half
  const int y    = blockIdx.x;
  const int b    = blockIdx.y;
  const int co0  = wv * 32;

  const float mx = wave_max256(bmx);
  const float sx = mx / 127.0f;

  // ---- prologue: quantize 3 rows into LDS ----
  const int g  = t >> 5;              // cin octet 0..7
  const int xx = t & 31;
  const int k16w = g >> 1, kbw = g & 1;
  if (t < 48) {                       // zero the xs=0 / xs=33 column halo
    const int r = t >> 4, q2 = t & 15;
    const int hk = q2 >> 2, hb = (q2 >> 1) & 1, hxs = (q2 & 1) * 33;
    *(short8*)&lds[(((r * 4 + hk) * 2 + hb) * 34 + hxs) * 8] = (short8)0;
  }
#pragma unroll
  for (int r = 0; r < 3; ++r) {
    const int yy = y + r - 1;
    short8 pk = (short8)0;
    if (yy >= 0 && yy < H_) {         // wave-uniform branch
#pragma unroll
      for (int j = 0; j < 8; ++j) {
        const float v = x[((b * CIN + g * 8 + j) * H_ + yy) * W_ + xx];
        float q = rintf(v / sx);
        q = fminf(fmaxf(q, -127.0f), 127.0f);
        pk[j] = (short)f2bf(q);
      }
    }
    *(short8*)&lds[(((r * 4 + k16w) * 2 + kbw) * 34 + (xx + 1)) * 8] = pk;
  }
  __syncthreads();

  // ---- main MFMA loop ----
  float16v acc0 = (float16v)0.0f, acc1 = (float16v)0.0f;
  const unsigned short* __restrict__ wp = qw + kb * 1024 + (co0 + col) * 8;
#pragma unroll
  for (int kh = 0; kh < 3; ++kh) {
#pragma unroll
    for (int kw = 0; kw < 3; ++kw) {
      const int s = kh * 3 + kw;
#pragma unroll
      for (int k16 = 0; k16 < 4; ++k16) {
        short8 a  = *(const short8*)(wp + (s * 4 + k16) * 2048);
        short8 bf = *(const short8*)&lds[(((kh * 4 + k16) * 2 + kb) * 34 +
                                          col + kw) * 8];
        if (((s * 4 + k16) & 1) == 0)
          acc0 = __builtin_amdgcn_mfma_f32_32x32x16_bf16(a, bf, acc0, 0, 0, 0);
        else
          acc1 = __builtin_amdgcn_mfma_f32_32x32x16_bf16(a, bf, acc1, 0, 0, 0);
      }
    }
  }

  const float sc = sx * (bmw[0] / 127.0f);
  const float16v acc = acc0 + acc1;
#pragma unroll
  for (int r = 0; r < 16; ++r) {
    const int row  = (r & 3) + 8 * (r >> 2) + 4 * kb;
    const int cout = co0 + row;
    out[((b * COUT + cout) << 10) + y * W_ + col] = sc * acc[r] + bias[cout];
  }
}

// ---------------------------------------------------------------------------
extern "C" void kernel_launch(void* const* d_in, const int* in_sizes, int n_in,
                              void* d_out, int out_size, void* d_ws, size_t ws_size,
                              hipStream_t stream) {
  const float* x    = (const float*)d_in[0];
  const float* w    = (const float*)d_in[1];
  const float* bias = (const float*)d_in[2];
  float* out = (float*)d_out;

  // ws: bmx[256] | bmw[1] | pad | qw bf16 [9][4][2][128][8] (147 KB)
  float* bmx = (float*)d_ws;
  float* bmw = bmx + 256;
  unsigned short* qw = (unsigned short*)((char*)d_ws + 2048);

  prep_kernel<<<288, 256, 0, stream>>>((const float4*)x, (const float4*)w, w,
                                       bmx, bmw, qw);
  conv_mfma_kernel<<<dim3(32, 16), 256, 0, stream>>>(x, qw, bmx, bmw, bias, out);
}